// Round 1
// baseline (6807.391 us; speedup 1.0000x reference)
//
#include <hip/hip_runtime.h>

#define NDIM 2048
#define KDIM 4096
#define NN (NDIM * NDIM)

// ---------------- big NT GEMM: C[2048][2048] = A(2048x4096) * B(2048x4096)^T
// 128x128 tile, BK=8, 256 threads, 8x8 per thread.
__global__ __launch_bounds__(256) void gemm_nt_big(const float* __restrict__ A,
                                                   const float* __restrict__ B,
                                                   float* __restrict__ C) {
  __shared__ float As[8][128];
  __shared__ float Bs[8][128];
  const int t = threadIdx.x;
  const int tx = t & 15, ty = t >> 4;
  const int lr = t >> 1;        // 0..127 row to load
  const int lk = (t & 1) * 4;   // 0 or 4
  const float* Ap = A + (size_t)(blockIdx.y * 128 + lr) * KDIM + lk;
  const float* Bp = B + (size_t)(blockIdx.x * 128 + lr) * KDIM + lk;
  float acc[8][8];
#pragma unroll
  for (int r = 0; r < 8; ++r)
#pragma unroll
    for (int c = 0; c < 8; ++c) acc[r][c] = 0.f;

  for (int k0 = 0; k0 < KDIM; k0 += 8) {
    float4 av = *(const float4*)(Ap + k0);
    float4 bv = *(const float4*)(Bp + k0);
    __syncthreads();
    As[lk + 0][lr] = av.x; As[lk + 1][lr] = av.y;
    As[lk + 2][lr] = av.z; As[lk + 3][lr] = av.w;
    Bs[lk + 0][lr] = bv.x; Bs[lk + 1][lr] = bv.y;
    Bs[lk + 2][lr] = bv.z; Bs[lk + 3][lr] = bv.w;
    __syncthreads();
#pragma unroll
    for (int kk = 0; kk < 8; ++kk) {
      float ra[8], rb[8];
#pragma unroll
      for (int r = 0; r < 8; ++r) ra[r] = As[kk][ty * 8 + r];
#pragma unroll
      for (int c = 0; c < 8; ++c) rb[c] = Bs[kk][tx * 8 + c];
#pragma unroll
      for (int r = 0; r < 8; ++r)
#pragma unroll
        for (int c = 0; c < 8; ++c) acc[r][c] += ra[r] * rb[c];
    }
  }
#pragma unroll
  for (int r = 0; r < 8; ++r) {
    float* p = C + (size_t)(blockIdx.y * 128 + ty * 8 + r) * NDIM + blockIdx.x * 128 + tx * 8;
    float4 v0 = {acc[r][0], acc[r][1], acc[r][2], acc[r][3]};
    float4 v1 = {acc[r][4], acc[r][5], acc[r][6], acc[r][7]};
    *(float4*)p = v0;
    *(float4*)(p + 4) = v1;
  }
}

// ---------------- generic 64x64 tile GEMM: C = alpha*op(A)*B + beta*C
// TA=false: A is MxK row-major (lda).  TA=true: A is KxM row-major (lda), use A^T.
// B is KxN row-major (ldb). M,N multiples of 64; K multiple of 16.
template <bool TA>
__global__ __launch_bounds__(256) void gemm_tile64(const float* __restrict__ A,
                                                   const float* __restrict__ B,
                                                   float* C, int M, int N, int K,
                                                   int lda, int ldb, int ldc,
                                                   float alpha, float beta) {
  __shared__ float As[16][64];
  __shared__ float Bs[16][64];
  const int t = threadIdx.x;
  const int tx = t & 15, ty = t >> 4;
  const int i0 = blockIdx.y * 64, j0 = blockIdx.x * 64;
  float acc[4][4];
#pragma unroll
  for (int r = 0; r < 4; ++r)
#pragma unroll
    for (int c = 0; c < 4; ++c) acc[r][c] = 0.f;

  for (int k0 = 0; k0 < K; k0 += 16) {
    float4 av, bv;
    if (TA) {
      av = *(const float4*)(A + (size_t)(k0 + ty) * lda + i0 + tx * 4);
    } else {
      av = *(const float4*)(A + (size_t)(i0 + (t >> 2)) * lda + k0 + (t & 3) * 4);
    }
    bv = *(const float4*)(B + (size_t)(k0 + ty) * ldb + j0 + tx * 4);
    __syncthreads();
    if (TA) {
      *(float4*)&As[ty][tx * 4] = av;
    } else {
      const int i = t >> 2, k4 = (t & 3) * 4;
      As[k4 + 0][i] = av.x; As[k4 + 1][i] = av.y;
      As[k4 + 2][i] = av.z; As[k4 + 3][i] = av.w;
    }
    *(float4*)&Bs[ty][tx * 4] = bv;
    __syncthreads();
#pragma unroll
    for (int kk = 0; kk < 16; ++kk) {
      float ra[4], rb[4];
#pragma unroll
      for (int r = 0; r < 4; ++r) ra[r] = As[kk][ty * 4 + r];
#pragma unroll
      for (int c = 0; c < 4; ++c) rb[c] = Bs[kk][tx * 4 + c];
#pragma unroll
      for (int r = 0; r < 4; ++r)
#pragma unroll
        for (int c = 0; c < 4; ++c) acc[r][c] += ra[r] * rb[c];
    }
  }
#pragma unroll
  for (int r = 0; r < 4; ++r) {
    float* p = C + (size_t)(i0 + ty * 4 + r) * ldc + j0 + tx * 4;
    float4 old = *(const float4*)p;
    float4 v;
    v.x = alpha * acc[r][0] + beta * old.x;
    v.y = alpha * acc[r][1] + beta * old.y;
    v.z = alpha * acc[r][2] + beta * old.z;
    v.w = alpha * acc[r][3] + beta * old.w;
    *(float4*)p = v;
  }
}

// ---------------- E = 0.5*(E + P) + 0.5*(R - R^T)   (eps*I is below fp32 ulp here)
__global__ __launch_bounds__(256) void make_E(float* E, const float* __restrict__ P,
                                              const float* __restrict__ R) {
  __shared__ float Rt[64][65];
  const int bi = blockIdx.y, bj = blockIdx.x;
  const int t = threadIdx.x;
  for (int idx = t; idx < 4096; idx += 256) {
    int r = idx >> 6, c = idx & 63;
    Rt[r][c] = R[(size_t)(bj * 64 + r) * NDIM + bi * 64 + c];
  }
  __syncthreads();
  for (int idx = t; idx < 4096; idx += 256) {
    int r = idx >> 6, c = idx & 63;
    size_t off = (size_t)(bi * 64 + r) * NDIM + bj * 64 + c;
    E[off] = 0.5f * (E[off] + P[off]) + 0.5f * (R[off] - Rt[c][r]);
  }
}

// ---------------- LU (no pivot) of 64x64 diag block at E[k][k], in LDS
__global__ __launch_bounds__(256) void lu_diag(float* E, int k) {
  __shared__ float S[64][65];
  const int t = threadIdx.x;
  for (int idx = t; idx < 4096; idx += 256)
    S[idx >> 6][idx & 63] = E[(size_t)(k + (idx >> 6)) * NDIM + k + (idx & 63)];
  __syncthreads();
  const int row = t & 63, cw = t >> 6;  // 4 column workers per row
  for (int j = 0; j < 63; ++j) {
    float rp = 1.0f / S[j][j];
    if (row > j && cw == 0) S[row][j] = S[row][j] * rp;
    __syncthreads();
    if (row > j) {
      float lv = S[row][j];
      for (int c = j + 1 + cw; c < 64; c += 4) S[row][c] -= lv * S[j][c];
    }
    __syncthreads();
  }
  for (int idx = t; idx < 4096; idx += 256)
    E[(size_t)(k + (idx >> 6)) * NDIM + k + (idx & 63)] = S[idx >> 6][idx & 63];
}

// ---------------- L21 = A21 * U11^{-1}: one thread per row below the diag block
__global__ __launch_bounds__(256) void lu_ptrsm(float* E, int k) {
  __shared__ float U[64][65];
  __shared__ float rd[64];
  const int t = threadIdx.x;
  for (int idx = t; idx < 4096; idx += 256)
    U[idx >> 6][idx & 63] = E[(size_t)(k + (idx >> 6)) * NDIM + k + (idx & 63)];
  __syncthreads();
  if (t < 64) rd[t] = 1.0f / U[t][t];
  __syncthreads();
  const int row = k + 64 + blockIdx.x * 256 + t;
  if (row >= NDIM) return;
  float* pr = E + (size_t)row * NDIM + k;
  float x[64];
#pragma unroll
  for (int c4 = 0; c4 < 64; c4 += 4) {
    float4 v = *(const float4*)(pr + c4);
    x[c4 + 0] = v.x; x[c4 + 1] = v.y; x[c4 + 2] = v.z; x[c4 + 3] = v.w;
  }
#pragma unroll
  for (int c = 0; c < 64; ++c) {
    float xc = x[c];
#pragma unroll
    for (int p = 0; p < c; ++p) xc -= x[p] * U[p][c];
    x[c] = xc * rd[c];
  }
#pragma unroll
  for (int c4 = 0; c4 < 64; c4 += 4) {
    float4 v = {x[c4 + 0], x[c4 + 1], x[c4 + 2], x[c4 + 3]};
    *(float4*)(pr + c4) = v;
  }
}

// ---------------- forward TRSM with unit-lower diag block L at E[k][k]:
// solve L * X = X in place for columns [colbase, colbase+ncols) of X (ld = NDIM)
__global__ __launch_bounds__(256) void trsm_fwd(const float* E, float* X, int k,
                                                int colbase, int ncols) {
  __shared__ float Lb[64][65];
  const int t = threadIdx.x;
  for (int idx = t; idx < 4096; idx += 256)
    Lb[idx >> 6][idx & 63] = E[(size_t)(k + (idx >> 6)) * NDIM + k + (idx & 63)];
  __syncthreads();
  const int col = colbase + blockIdx.x * 256 + t;
  if (col >= colbase + ncols) return;
  float x[64];
#pragma unroll
  for (int j = 0; j < 64; ++j) {
    float xj = X[(size_t)(k + j) * NDIM + col];
#pragma unroll
    for (int i = 0; i < j; ++i) xj -= Lb[j][i] * x[i];
    x[j] = xj;
  }
#pragma unroll
  for (int j = 0; j < 64; ++j) X[(size_t)(k + j) * NDIM + col] = x[j];
}

// ---------------- backward TRSM with upper U at E[k][k]: solve U * X = X in place
__global__ __launch_bounds__(256) void trsm_bwd(const float* E, float* X, int k) {
  __shared__ float Ub[64][65];
  __shared__ float rd[64];
  const int t = threadIdx.x;
  for (int idx = t; idx < 4096; idx += 256)
    Ub[idx >> 6][idx & 63] = E[(size_t)(k + (idx >> 6)) * NDIM + k + (idx & 63)];
  __syncthreads();
  if (t < 64) rd[t] = 1.0f / Ub[t][t];
  __syncthreads();
  const int col = blockIdx.x * 256 + t;
  float x[64];
#pragma unroll
  for (int j = 63; j >= 0; --j) {
    float xj = X[(size_t)(k + j) * NDIM + col];
#pragma unroll
    for (int i = j + 1; i < 64; ++i) xj -= Ub[j][i] * x[i];
    x[j] = xj * rd[j];
  }
#pragma unroll
  for (int j = 0; j < 64; ++j) X[(size_t)(k + j) * NDIM + col] = x[j];
}

extern "C" void kernel_launch(void* const* d_in, const int* in_sizes, int n_in,
                              void* d_out, int out_size, void* d_ws, size_t ws_size,
                              hipStream_t stream) {
  const float* L = (const float*)d_in[0];
  const float* R = (const float*)d_in[1];
  const float* Bin = (const float*)d_in[2];

  float* ws = (float*)d_ws;
  float* P = ws;                         // 2048^2
  float* F = ws + (size_t)NN;            // 2048^2, becomes Y then Acl
  float* C1 = ws + (size_t)2 * NN;       // 256 x 2048
  float* W = C1 + (size_t)256 * NDIM;    // 256 x 2048
  float* E = (float*)d_out;              // LU factors live in d_out until the end

  const float* L1 = L;
  const float* L2 = L + (size_t)NDIM * KDIM;

  dim3 g16(16, 16);
  gemm_nt_big<<<g16, 256, 0, stream>>>(L2, L2, P);  // P  = L2 L2^T
  gemm_nt_big<<<g16, 256, 0, stream>>>(L2, L1, F);  // F  = L2 L1^T
  gemm_nt_big<<<g16, 256, 0, stream>>>(L1, L1, E);  // E  = L1 L1^T (pre-combine)
  make_E<<<dim3(32, 32), 256, 0, stream>>>(E, P, R);

  // ---- LU (no pivoting), NB = 64
  for (int k = 0; k < NDIM; k += 64) {
    lu_diag<<<1, 256, 0, stream>>>(E, k);
    int rem = NDIM - k - 64;
    if (rem > 0) {
      lu_ptrsm<<<(rem + 255) / 256, 256, 0, stream>>>(E, k);
      trsm_fwd<<<(rem + 255) / 256, 256, 0, stream>>>(E, E, k, k + 64, rem);
      dim3 gs(rem / 64, rem / 64);
      gemm_tile64<false><<<gs, 256, 0, stream>>>(
          E + (size_t)(k + 64) * NDIM + k, E + (size_t)k * NDIM + (k + 64),
          E + (size_t)(k + 64) * NDIM + (k + 64), rem, rem, 64, NDIM, NDIM, NDIM,
          -1.f, 1.f);
    }
  }

  // ---- forward solve L Y = F (in place on F)
  for (int k = 0; k < NDIM; k += 64) {
    trsm_fwd<<<8, 256, 0, stream>>>(E, F, k, 0, NDIM);
    int rem = NDIM - k - 64;
    if (rem > 0)
      gemm_tile64<false><<<dim3(32, rem / 64), 256, 0, stream>>>(
          E + (size_t)(k + 64) * NDIM + k, F + (size_t)k * NDIM,
          F + (size_t)(k + 64) * NDIM, rem, NDIM, 64, NDIM, NDIM, NDIM, -1.f, 1.f);
  }
  // ---- backward solve U X = Y (in place on F -> Acl)
  for (int k = NDIM - 64; k >= 0; k -= 64) {
    trsm_bwd<<<8, 256, 0, stream>>>(E, F, k);
    if (k > 0)
      gemm_tile64<false><<<dim3(32, k / 64), 256, 0, stream>>>(
          E + k, F + (size_t)k * NDIM, F, k, NDIM, 64, NDIM, NDIM, NDIM, -1.f, 1.f);
  }

  // ---- C1 = B^T P  (256 x 2048)
  gemm_tile64<true><<<dim3(32, 4), 256, 0, stream>>>(Bin, P, C1, 256, NDIM, NDIM,
                                                     256, NDIM, NDIM, 1.f, 0.f);
  // ---- W = C1 * Acl  (256 x 2048)
  gemm_tile64<false><<<dim3(32, 4), 256, 0, stream>>>(C1, F, W, 256, NDIM, NDIM,
                                                      NDIM, NDIM, NDIM, 1.f, 0.f);
  // ---- Acl -= B * W  (in place on F), then copy out
  gemm_tile64<false><<<dim3(32, 32), 256, 0, stream>>>(Bin, W, F, NDIM, NDIM, 256,
                                                       256, NDIM, NDIM, -1.f, 1.f);
  hipMemcpyAsync(d_out, F, (size_t)NN * sizeof(float), hipMemcpyDeviceToDevice,
                 stream);
}

// Round 2
// 5336.480 us; speedup vs baseline: 1.2756x; 1.2756x over previous
//
#include <hip/hip_runtime.h>

#define NDIM 2048
#define KDIM 4096
#define NN (NDIM * NDIM)

// ---------------- big NT GEMM: C[2048][2048] = A(2048x4096) * B(2048x4096)^T
// 128x128 tile, BK=16, 256 threads, 8x8 per thread, double-buffered LDS +
// register prefetch. B-side per-thread cols split (tx*4, 64+tx*4) to keep
// ds_read_b128 at 2-way bank aliasing (free) instead of 4-way.
__global__ __launch_bounds__(256) void gemm_nt_big(const float* __restrict__ A,
                                                   const float* __restrict__ B,
                                                   float* __restrict__ C) {
  __shared__ float As[2][16][128];
  __shared__ float Bs[2][16][128];
  const int t = threadIdx.x;
  const int tx = t & 15, ty = t >> 4;
  const int lr = t >> 1;        // 0..127 row to load
  const int lk = (t & 1) * 8;   // 0 or 8
  const float* Ap = A + (size_t)(blockIdx.y * 128 + lr) * KDIM + lk;
  const float* Bp = B + (size_t)(blockIdx.x * 128 + lr) * KDIM + lk;
  float acc[8][8];
#pragma unroll
  for (int r = 0; r < 8; ++r)
#pragma unroll
    for (int c = 0; c < 8; ++c) acc[r][c] = 0.f;

  // prologue: tile 0 -> buf 0
  {
    float4 a0 = *(const float4*)Ap, a1 = *(const float4*)(Ap + 4);
    float4 b0 = *(const float4*)Bp, b1 = *(const float4*)(Bp + 4);
    As[0][lk + 0][lr] = a0.x; As[0][lk + 1][lr] = a0.y;
    As[0][lk + 2][lr] = a0.z; As[0][lk + 3][lr] = a0.w;
    As[0][lk + 4][lr] = a1.x; As[0][lk + 5][lr] = a1.y;
    As[0][lk + 6][lr] = a1.z; As[0][lk + 7][lr] = a1.w;
    Bs[0][lk + 0][lr] = b0.x; Bs[0][lk + 1][lr] = b0.y;
    Bs[0][lk + 2][lr] = b0.z; Bs[0][lk + 3][lr] = b0.w;
    Bs[0][lk + 4][lr] = b1.x; Bs[0][lk + 5][lr] = b1.y;
    Bs[0][lk + 6][lr] = b1.z; Bs[0][lk + 7][lr] = b1.w;
  }
  int cur = 0;
  for (int k0 = 0; k0 < KDIM; k0 += 16) {
    float4 na0, na1, nb0, nb1;
    const bool more = (k0 + 16) < KDIM;
    if (more) {
      na0 = *(const float4*)(Ap + k0 + 16); na1 = *(const float4*)(Ap + k0 + 20);
      nb0 = *(const float4*)(Bp + k0 + 16); nb1 = *(const float4*)(Bp + k0 + 20);
    }
    __syncthreads();
#pragma unroll
    for (int kk = 0; kk < 16; ++kk) {
      float ra[8], rb[8];
#pragma unroll
      for (int r = 0; r < 8; ++r) ra[r] = As[cur][kk][ty * 8 + r];
#pragma unroll
      for (int c = 0; c < 4; ++c) {
        rb[c] = Bs[cur][kk][tx * 4 + c];
        rb[4 + c] = Bs[cur][kk][64 + tx * 4 + c];
      }
#pragma unroll
      for (int r = 0; r < 8; ++r)
#pragma unroll
        for (int c = 0; c < 8; ++c) acc[r][c] += ra[r] * rb[c];
    }
    if (more) {
      const int nx = cur ^ 1;
      As[nx][lk + 0][lr] = na0.x; As[nx][lk + 1][lr] = na0.y;
      As[nx][lk + 2][lr] = na0.z; As[nx][lk + 3][lr] = na0.w;
      As[nx][lk + 4][lr] = na1.x; As[nx][lk + 5][lr] = na1.y;
      As[nx][lk + 6][lr] = na1.z; As[nx][lk + 7][lr] = na1.w;
      Bs[nx][lk + 0][lr] = nb0.x; Bs[nx][lk + 1][lr] = nb0.y;
      Bs[nx][lk + 2][lr] = nb0.z; Bs[nx][lk + 3][lr] = nb0.w;
      Bs[nx][lk + 4][lr] = nb1.x; Bs[nx][lk + 5][lr] = nb1.y;
      Bs[nx][lk + 6][lr] = nb1.z; Bs[nx][lk + 7][lr] = nb1.w;
    }
    cur ^= 1;
  }
#pragma unroll
  for (int r = 0; r < 8; ++r) {
    float* p0 = C + (size_t)(blockIdx.y * 128 + ty * 8 + r) * NDIM + blockIdx.x * 128 + tx * 4;
    float4 v0 = {acc[r][0], acc[r][1], acc[r][2], acc[r][3]};
    float4 v1 = {acc[r][4], acc[r][5], acc[r][6], acc[r][7]};
    *(float4*)p0 = v0;
    *(float4*)(p0 + 64) = v1;
  }
}

// ---------------- generic 64x64 tile GEMM: C = alpha*op(A)*B + beta*C
template <bool TA>
__global__ __launch_bounds__(256) void gemm_tile64(const float* __restrict__ A,
                                                   const float* __restrict__ B,
                                                   float* C, int M, int N, int K,
                                                   int lda, int ldb, int ldc,
                                                   float alpha, float beta) {
  __shared__ float As[16][64];
  __shared__ float Bs[16][64];
  const int t = threadIdx.x;
  const int tx = t & 15, ty = t >> 4;
  const int i0 = blockIdx.y * 64, j0 = blockIdx.x * 64;
  float acc[4][4];
#pragma unroll
  for (int r = 0; r < 4; ++r)
#pragma unroll
    for (int c = 0; c < 4; ++c) acc[r][c] = 0.f;

  for (int k0 = 0; k0 < K; k0 += 16) {
    float4 av, bv;
    if (TA) {
      av = *(const float4*)(A + (size_t)(k0 + ty) * lda + i0 + tx * 4);
    } else {
      av = *(const float4*)(A + (size_t)(i0 + (t >> 2)) * lda + k0 + (t & 3) * 4);
    }
    bv = *(const float4*)(B + (size_t)(k0 + ty) * ldb + j0 + tx * 4);
    __syncthreads();
    if (TA) {
      *(float4*)&As[ty][tx * 4] = av;
    } else {
      const int i = t >> 2, k4 = (t & 3) * 4;
      As[k4 + 0][i] = av.x; As[k4 + 1][i] = av.y;
      As[k4 + 2][i] = av.z; As[k4 + 3][i] = av.w;
    }
    *(float4*)&Bs[ty][tx * 4] = bv;
    __syncthreads();
#pragma unroll
    for (int kk = 0; kk < 16; ++kk) {
      float ra[4], rb[4];
#pragma unroll
      for (int r = 0; r < 4; ++r) ra[r] = As[kk][ty * 4 + r];
#pragma unroll
      for (int c = 0; c < 4; ++c) rb[c] = Bs[kk][tx * 4 + c];
#pragma unroll
      for (int r = 0; r < 4; ++r)
#pragma unroll
        for (int c = 0; c < 4; ++c) acc[r][c] += ra[r] * rb[c];
    }
  }
#pragma unroll
  for (int r = 0; r < 4; ++r) {
    float* p = C + (size_t)(i0 + ty * 4 + r) * ldc + j0 + tx * 4;
    float4 old = *(const float4*)p;
    float4 v;
    v.x = alpha * acc[r][0] + beta * old.x;
    v.y = alpha * acc[r][1] + beta * old.y;
    v.z = alpha * acc[r][2] + beta * old.z;
    v.w = alpha * acc[r][3] + beta * old.w;
    *(float4*)p = v;
  }
}

// ---------------- E = 0.5*(E + P) + 0.5*(R - R^T)
__global__ __launch_bounds__(256) void make_E(float* E, const float* __restrict__ P,
                                              const float* __restrict__ R) {
  __shared__ float Rt[64][65];
  const int bi = blockIdx.y, bj = blockIdx.x;
  const int t = threadIdx.x;
  for (int idx = t; idx < 4096; idx += 256) {
    int r = idx >> 6, c = idx & 63;
    Rt[r][c] = R[(size_t)(bj * 64 + r) * NDIM + bi * 64 + c];
  }
  __syncthreads();
  for (int idx = t; idx < 4096; idx += 256) {
    int r = idx >> 6, c = idx & 63;
    size_t off = (size_t)(bi * 64 + r) * NDIM + bj * 64 + c;
    E[off] = 0.5f * (E[off] + P[off]) + 0.5f * (R[off] - Rt[c][r]);
  }
}

// ---------------- LU (no pivot) of 64x64 diag block at E[k][k], in LDS
__global__ __launch_bounds__(256) void lu_diag(float* E, int k) {
  __shared__ float S[64][65];
  const int t = threadIdx.x;
  for (int idx = t; idx < 4096; idx += 256)
    S[idx >> 6][idx & 63] = E[(size_t)(k + (idx >> 6)) * NDIM + k + (idx & 63)];
  __syncthreads();
  const int row = t & 63, cw = t >> 6;
  for (int j = 0; j < 63; ++j) {
    float rp = 1.0f / S[j][j];
    if (row > j && cw == 0) S[row][j] = S[row][j] * rp;
    __syncthreads();
    if (row > j) {
      float lv = S[row][j];
      for (int c = j + 1 + cw; c < 64; c += 4) S[row][c] -= lv * S[j][c];
    }
    __syncthreads();
  }
  for (int idx = t; idx < 4096; idx += 256)
    E[(size_t)(k + (idx >> 6)) * NDIM + k + (idx & 63)] = S[idx >> 6][idx & 63];
}

// ---------------- merged panels: blocks [0,nb) do L21 = A21*U11^-1 (rows below),
// blocks [nb,2nb) do U12 = L11^-1*A12 (row panel to the right).
__global__ __launch_bounds__(256) void lu_panels(float* __restrict__ E, int k, int nb) {
  __shared__ float D[64 * 65];
  __shared__ float rd[64];
  const int t = threadIdx.x;
  for (int idx = t; idx < 4096; idx += 256)
    D[(idx >> 6) * 65 + (idx & 63)] = E[(size_t)(k + (idx >> 6)) * NDIM + k + (idx & 63)];
  __syncthreads();
  if (t < 64) rd[t] = 1.0f / D[t * 65 + t];
  __syncthreads();
  if ((int)blockIdx.x < nb) {
    const int row = k + 64 + blockIdx.x * 256 + t;
    if (row >= NDIM) return;
    float* pr = E + (size_t)row * NDIM + k;
    float x[64];
#pragma unroll
    for (int c4 = 0; c4 < 64; c4 += 4) {
      float4 v = *(const float4*)(pr + c4);
      x[c4 + 0] = v.x; x[c4 + 1] = v.y; x[c4 + 2] = v.z; x[c4 + 3] = v.w;
    }
#pragma unroll
    for (int c = 0; c < 64; ++c) {
      float xc = x[c];
#pragma unroll
      for (int p = 0; p < c; ++p) xc -= x[p] * D[p * 65 + c];
      x[c] = xc * rd[c];
    }
#pragma unroll
    for (int c4 = 0; c4 < 64; c4 += 4) {
      float4 v = {x[c4 + 0], x[c4 + 1], x[c4 + 2], x[c4 + 3]};
      *(float4*)(pr + c4) = v;
    }
  } else {
    const int col = k + 64 + ((int)blockIdx.x - nb) * 256 + t;
    if (col >= NDIM) return;
    float x[64];
#pragma unroll
    for (int j = 0; j < 64; ++j) {
      float xj = E[(size_t)(k + j) * NDIM + col];
#pragma unroll
      for (int i = 0; i < j; ++i) xj -= D[j * 65 + i] * x[i];
      x[j] = xj;
    }
#pragma unroll
    for (int j = 0; j < 64; ++j) E[(size_t)(k + j) * NDIM + col] = x[j];
  }
}

// ---------------- trailing update E22 -= L21*U12 (K=64); block(0,0) then
// LU-factors its (diagonal) tile in LDS before storing.
__global__ __launch_bounds__(256) void lu_update(float* __restrict__ E, int k) {
  __shared__ float sh[64 * 65];
  float* As = sh;
  float* Bs = sh + 1024;
  const int t = threadIdx.x;
  const int tx = t & 15, ty = t >> 4;
  const int i0 = k + 64 + blockIdx.y * 64;
  const int j0 = k + 64 + blockIdx.x * 64;
  const float* A = E + (size_t)i0 * NDIM + k;
  const float* Bm = E + (size_t)k * NDIM + j0;
  float acc[4][4];
#pragma unroll
  for (int r = 0; r < 4; ++r)
#pragma unroll
    for (int c = 0; c < 4; ++c) acc[r][c] = 0.f;
  for (int k0 = 0; k0 < 64; k0 += 16) {
    float4 av = *(const float4*)(A + (size_t)(t >> 2) * NDIM + k0 + (t & 3) * 4);
    float4 bv = *(const float4*)(Bm + (size_t)(k0 + ty) * NDIM + tx * 4);
    __syncthreads();
    const int i = t >> 2, k4 = (t & 3) * 4;
    As[(k4 + 0) * 64 + i] = av.x; As[(k4 + 1) * 64 + i] = av.y;
    As[(k4 + 2) * 64 + i] = av.z; As[(k4 + 3) * 64 + i] = av.w;
    *(float4*)&Bs[ty * 64 + tx * 4] = bv;
    __syncthreads();
#pragma unroll
    for (int kk = 0; kk < 16; ++kk) {
      float ra[4], rb[4];
#pragma unroll
      for (int r = 0; r < 4; ++r) ra[r] = As[kk * 64 + ty * 4 + r];
#pragma unroll
      for (int c = 0; c < 4; ++c) rb[c] = Bs[kk * 64 + tx * 4 + c];
#pragma unroll
      for (int r = 0; r < 4; ++r)
#pragma unroll
        for (int c = 0; c < 4; ++c) acc[r][c] += ra[r] * rb[c];
    }
  }
  float* Cp = E + (size_t)i0 * NDIM + j0;
  if (blockIdx.x == 0 && blockIdx.y == 0) {
    __syncthreads();  // done reading As/Bs; reuse sh as the 64x65 tile
#pragma unroll
    for (int r = 0; r < 4; ++r) {
      float4 old = *(const float4*)(Cp + (size_t)(ty * 4 + r) * NDIM + tx * 4);
      sh[(ty * 4 + r) * 65 + tx * 4 + 0] = old.x - acc[r][0];
      sh[(ty * 4 + r) * 65 + tx * 4 + 1] = old.y - acc[r][1];
      sh[(ty * 4 + r) * 65 + tx * 4 + 2] = old.z - acc[r][2];
      sh[(ty * 4 + r) * 65 + tx * 4 + 3] = old.w - acc[r][3];
    }
    __syncthreads();
    const int row = t & 63, cw = t >> 6;
    for (int j = 0; j < 63; ++j) {
      float rp = 1.0f / sh[j * 65 + j];
      if (row > j && cw == 0) sh[row * 65 + j] *= rp;
      __syncthreads();
      if (row > j) {
        float lv = sh[row * 65 + j];
        for (int c = j + 1 + cw; c < 64; c += 4) sh[row * 65 + c] -= lv * sh[j * 65 + c];
      }
      __syncthreads();
    }
    for (int idx = t; idx < 4096; idx += 256)
      Cp[(size_t)(idx >> 6) * NDIM + (idx & 63)] = sh[(idx >> 6) * 65 + (idx & 63)];
  } else {
#pragma unroll
    for (int r = 0; r < 4; ++r) {
      float* p = Cp + (size_t)(ty * 4 + r) * NDIM + tx * 4;
      float4 old = *(const float4*)p;
      float4 v = {old.x - acc[r][0], old.y - acc[r][1], old.z - acc[r][2],
                  old.w - acc[r][3]};
      *(float4*)p = v;
    }
  }
}

// ---------------- fwd solve fused: F[k+64+by*64 ..][bx*64..] -= L*Y_k; blocks
// with by==0 then forward-solve their 64 rows (rows k+64..k+128).
__global__ __launch_bounds__(256) void fwd_update(const float* __restrict__ E,
                                                  float* __restrict__ F, int k) {
  __shared__ float sh[2 * 64 * 65];
  float* As = sh;
  float* Bs = sh + 1024;
  const int t = threadIdx.x;
  const int tx = t & 15, ty = t >> 4;
  const int i0 = k + 64 + blockIdx.y * 64;
  const int j0 = blockIdx.x * 64;
  const float* A = E + (size_t)i0 * NDIM + k;
  const float* Bm = F + (size_t)k * NDIM + j0;
  float acc[4][4];
#pragma unroll
  for (int r = 0; r < 4; ++r)
#pragma unroll
    for (int c = 0; c < 4; ++c) acc[r][c] = 0.f;
  for (int k0 = 0; k0 < 64; k0 += 16) {
    float4 av = *(const float4*)(A + (size_t)(t >> 2) * NDIM + k0 + (t & 3) * 4);
    float4 bv = *(const float4*)(Bm + (size_t)(k0 + ty) * NDIM + tx * 4);
    __syncthreads();
    const int i = t >> 2, k4 = (t & 3) * 4;
    As[(k4 + 0) * 64 + i] = av.x; As[(k4 + 1) * 64 + i] = av.y;
    As[(k4 + 2) * 64 + i] = av.z; As[(k4 + 3) * 64 + i] = av.w;
    *(float4*)&Bs[ty * 64 + tx * 4] = bv;
    __syncthreads();
#pragma unroll
    for (int kk = 0; kk < 16; ++kk) {
      float ra[4], rb[4];
#pragma unroll
      for (int r = 0; r < 4; ++r) ra[r] = As[kk * 64 + ty * 4 + r];
#pragma unroll
      for (int c = 0; c < 4; ++c) rb[c] = Bs[kk * 64 + tx * 4 + c];
#pragma unroll
      for (int r = 0; r < 4; ++r)
#pragma unroll
        for (int c = 0; c < 4; ++c) acc[r][c] += ra[r] * rb[c];
    }
  }
  float* Cp = F + (size_t)i0 * NDIM + j0;
  if (blockIdx.y == 0) {
    float* S = sh;           // 64x65 updated tile (by columns for the solve)
    float* Lb = sh + 4160;   // 64x65 diag L block
    __syncthreads();
    for (int idx = t; idx < 4096; idx += 256)
      Lb[(idx >> 6) * 65 + (idx & 63)] =
          E[(size_t)(i0 + (idx >> 6)) * NDIM + i0 + (idx & 63)];
#pragma unroll
    for (int r = 0; r < 4; ++r) {
      float4 old = *(const float4*)(Cp + (size_t)(ty * 4 + r) * NDIM + tx * 4);
      S[(ty * 4 + r) * 65 + tx * 4 + 0] = old.x - acc[r][0];
      S[(ty * 4 + r) * 65 + tx * 4 + 1] = old.y - acc[r][1];
      S[(ty * 4 + r) * 65 + tx * 4 + 2] = old.z - acc[r][2];
      S[(ty * 4 + r) * 65 + tx * 4 + 3] = old.w - acc[r][3];
    }
    __syncthreads();
    if (t < 64) {
      float x[64];
#pragma unroll
      for (int j = 0; j < 64; ++j) {
        float xj = S[j * 65 + t];
#pragma unroll
        for (int i = 0; i < j; ++i) xj -= Lb[j * 65 + i] * x[i];
        x[j] = xj;
      }
#pragma unroll
      for (int j = 0; j < 64; ++j) Cp[(size_t)j * NDIM + t] = x[j];
    }
  } else {
#pragma unroll
    for (int r = 0; r < 4; ++r) {
      float* p = Cp + (size_t)(ty * 4 + r) * NDIM + tx * 4;
      float4 old = *(const float4*)p;
      float4 v = {old.x - acc[r][0], old.y - acc[r][1], old.z - acc[r][2],
                  old.w - acc[r][3]};
      *(float4*)p = v;
    }
  }
}

// ---------------- bwd solve fused: F[by*64..][bx*64..] -= U[..,k..k+64)*X_k;
// blocks with by==k/64-1 then back-solve their 64 rows (rows k-64..k).
__global__ __launch_bounds__(256) void bwd_update(const float* __restrict__ E,
                                                  float* __restrict__ F, int k) {
  __shared__ float sh[2 * 64 * 65 + 64];
  float* As = sh;
  float* Bs = sh + 1024;
  const int t = threadIdx.x;
  const int tx = t & 15, ty = t >> 4;
  const int i0 = blockIdx.y * 64;
  const int j0 = blockIdx.x * 64;
  const float* A = E + (size_t)i0 * NDIM + k;
  const float* Bm = F + (size_t)k * NDIM + j0;
  float acc[4][4];
#pragma unroll
  for (int r = 0; r < 4; ++r)
#pragma unroll
    for (int c = 0; c < 4; ++c) acc[r][c] = 0.f;
  for (int k0 = 0; k0 < 64; k0 += 16) {
    float4 av = *(const float4*)(A + (size_t)(t >> 2) * NDIM + k0 + (t & 3) * 4);
    float4 bv = *(const float4*)(Bm + (size_t)(k0 + ty) * NDIM + tx * 4);
    __syncthreads();
    const int i = t >> 2, k4 = (t & 3) * 4;
    As[(k4 + 0) * 64 + i] = av.x; As[(k4 + 1) * 64 + i] = av.y;
    As[(k4 + 2) * 64 + i] = av.z; As[(k4 + 3) * 64 + i] = av.w;
    *(float4*)&Bs[ty * 64 + tx * 4] = bv;
    __syncthreads();
#pragma unroll
    for (int kk = 0; kk < 16; ++kk) {
      float ra[4], rb[4];
#pragma unroll
      for (int r = 0; r < 4; ++r) ra[r] = As[kk * 64 + ty * 4 + r];
#pragma unroll
      for (int c = 0; c < 4; ++c) rb[c] = Bs[kk * 64 + tx * 4 + c];
#pragma unroll
      for (int r = 0; r < 4; ++r)
#pragma unroll
        for (int c = 0; c < 4; ++c) acc[r][c] += ra[r] * rb[c];
    }
  }
  float* Cp = F + (size_t)i0 * NDIM + j0;
  if ((int)blockIdx.y == (k >> 6) - 1) {
    float* S = sh;            // 64x65 updated tile
    float* Ub = sh + 4160;    // 64x65 diag U block
    float* rd = sh + 8320;
    __syncthreads();
    for (int idx = t; idx < 4096; idx += 256)
      Ub[(idx >> 6) * 65 + (idx & 63)] =
          E[(size_t)(i0 + (idx >> 6)) * NDIM + i0 + (idx & 63)];
#pragma unroll
    for (int r = 0; r < 4; ++r) {
      float4 old = *(const float4*)(Cp + (size_t)(ty * 4 + r) * NDIM + tx * 4);
      S[(ty * 4 + r) * 65 + tx * 4 + 0] = old.x - acc[r][0];
      S[(ty * 4 + r) * 65 + tx * 4 + 1] = old.y - acc[r][1];
      S[(ty * 4 + r) * 65 + tx * 4 + 2] = old.z - acc[r][2];
      S[(ty * 4 + r) * 65 + tx * 4 + 3] = old.w - acc[r][3];
    }
    __syncthreads();
    if (t < 64) rd[t] = 1.0f / Ub[t * 65 + t];
    __syncthreads();
    if (t < 64) {
      float x[64];
#pragma unroll
      for (int j = 63; j >= 0; --j) {
        float xj = S[j * 65 + t];
#pragma unroll
        for (int i = j + 1; i < 64; ++i) xj -= Ub[j * 65 + i] * x[i];
        x[j] = xj * rd[j];
      }
#pragma unroll
      for (int j = 0; j < 64; ++j) Cp[(size_t)j * NDIM + t] = x[j];
    }
  } else {
#pragma unroll
    for (int r = 0; r < 4; ++r) {
      float* p = Cp + (size_t)(ty * 4 + r) * NDIM + tx * 4;
      float4 old = *(const float4*)p;
      float4 v = {old.x - acc[r][0], old.y - acc[r][1], old.z - acc[r][2],
                  old.w - acc[r][3]};
      *(float4*)p = v;
    }
  }
}

// ---------------- standalone TRSMs for the first block-row of each solve
__global__ __launch_bounds__(256) void trsm_fwd(const float* E, float* X, int k,
                                                int colbase, int ncols) {
  __shared__ float Lb[64][65];
  const int t = threadIdx.x;
  for (int idx = t; idx < 4096; idx += 256)
    Lb[idx >> 6][idx & 63] = E[(size_t)(k + (idx >> 6)) * NDIM + k + (idx & 63)];
  __syncthreads();
  const int col = colbase + blockIdx.x * 256 + t;
  if (col >= colbase + ncols) return;
  float x[64];
#pragma unroll
  for (int j = 0; j < 64; ++j) {
    float xj = X[(size_t)(k + j) * NDIM + col];
#pragma unroll
    for (int i = 0; i < j; ++i) xj -= Lb[j][i] * x[i];
    x[j] = xj;
  }
#pragma unroll
  for (int j = 0; j < 64; ++j) X[(size_t)(k + j) * NDIM + col] = x[j];
}

__global__ __launch_bounds__(256) void trsm_bwd(const float* E, float* X, int k) {
  __shared__ float Ub[64][65];
  __shared__ float rd[64];
  const int t = threadIdx.x;
  for (int idx = t; idx < 4096; idx += 256)
    Ub[idx >> 6][idx & 63] = E[(size_t)(k + (idx >> 6)) * NDIM + k + (idx & 63)];
  __syncthreads();
  if (t < 64) rd[t] = 1.0f / Ub[t][t];
  __syncthreads();
  const int col = blockIdx.x * 256 + t;
  float x[64];
#pragma unroll
  for (int j = 63; j >= 0; --j) {
    float xj = X[(size_t)(k + j) * NDIM + col];
#pragma unroll
    for (int i = j + 1; i < 64; ++i) xj -= Ub[j][i] * x[i];
    x[j] = xj * rd[j];
  }
#pragma unroll
  for (int j = 0; j < 64; ++j) X[(size_t)(k + j) * NDIM + col] = x[j];
}

extern "C" void kernel_launch(void* const* d_in, const int* in_sizes, int n_in,
                              void* d_out, int out_size, void* d_ws, size_t ws_size,
                              hipStream_t stream) {
  const float* L = (const float*)d_in[0];
  const float* R = (const float*)d_in[1];
  const float* Bin = (const float*)d_in[2];

  float* ws = (float*)d_ws;
  float* P = ws;                         // 2048^2
  float* F = ws + (size_t)NN;            // 2048^2, becomes Y then Acl
  float* C1 = ws + (size_t)2 * NN;       // 256 x 2048
  float* W = C1 + (size_t)256 * NDIM;    // 256 x 2048
  float* E = (float*)d_out;              // LU factors live in d_out until the end

  const float* L1 = L;
  const float* L2 = L + (size_t)NDIM * KDIM;

  dim3 g16(16, 16);
  gemm_nt_big<<<g16, 256, 0, stream>>>(L2, L2, P);  // P  = L2 L2^T
  gemm_nt_big<<<g16, 256, 0, stream>>>(L2, L1, F);  // F  = L2 L1^T
  gemm_nt_big<<<g16, 256, 0, stream>>>(L1, L1, E);  // E  = L1 L1^T (pre-combine)
  make_E<<<dim3(32, 32), 256, 0, stream>>>(E, P, R);

  // ---- LU (no pivoting), NB = 64; diag LU fused into the trailing update
  lu_diag<<<1, 256, 0, stream>>>(E, 0);
  for (int k = 0; k + 64 < NDIM; k += 64) {
    const int rem = NDIM - k - 64;
    const int nb = (rem + 255) / 256;
    lu_panels<<<2 * nb, 256, 0, stream>>>(E, k, nb);
    lu_update<<<dim3(rem / 64, rem / 64), 256, 0, stream>>>(E, k);
  }

  // ---- forward solve L Y = F (in place on F), TRSM fused into updates
  trsm_fwd<<<8, 256, 0, stream>>>(E, F, 0, 0, NDIM);
  for (int k = 0; k + 64 < NDIM; k += 64)
    fwd_update<<<dim3(32, (NDIM - k - 64) / 64), 256, 0, stream>>>(E, F, k);

  // ---- backward solve U X = Y (in place on F -> Acl)
  trsm_bwd<<<8, 256, 0, stream>>>(E, F, NDIM - 64);
  for (int k = NDIM - 64; k >= 64; k -= 64)
    bwd_update<<<dim3(32, k / 64), 256, 0, stream>>>(E, F, k);

  // ---- A = (I - B (B^T P)) Acl
  gemm_tile64<true><<<dim3(32, 4), 256, 0, stream>>>(Bin, P, C1, 256, NDIM, NDIM,
                                                     256, NDIM, NDIM, 1.f, 0.f);
  gemm_tile64<false><<<dim3(32, 4), 256, 0, stream>>>(C1, F, W, 256, NDIM, NDIM,
                                                      NDIM, NDIM, NDIM, 1.f, 0.f);
  gemm_tile64<false><<<dim3(32, 32), 256, 0, stream>>>(Bin, W, F, NDIM, NDIM, 256,
                                                       256, NDIM, NDIM, -1.f, 1.f);
  hipMemcpyAsync(d_out, F, (size_t)NN * sizeof(float), hipMemcpyDeviceToDevice,
                 stream);
}